// Round 1
// baseline (336.181 us; speedup 1.0000x reference)
//
#include <hip/hip_runtime.h>
#include <math.h>

#define H_   23
#define W_   23
#define P_   529
#define TH_  0.05f
#define PADW 27          // 23 + 2*2 halo
#define NTHR 256

__global__ __launch_bounds__(NTHR) void peak_kernel(
    const float* __restrict__ tscores,  // [2,B,P]
    const float* __restrict__ anno,     // [1,B,P]
    const float* __restrict__ W1, const float* __restrict__ b1,
    const float* __restrict__ g1, const float* __restrict__ be1,
    const float* __restrict__ m1, const float* __restrict__ v1,
    const float* __restrict__ W2, const float* __restrict__ b2,
    const float* __restrict__ g2, const float* __restrict__ be2,
    const float* __restrict__ m2, const float* __restrict__ v2,
    const float* __restrict__ W3, const float* __restrict__ b3,
    float* __restrict__ out, int B)
{
    const int t    = threadIdx.x;
    const int b    = blockIdx.x;
    const int lane = t & 63;
    const int wv   = t >> 6;

    __shared__ float A[PADW * PADW];     // padded map (-inf border)
    __shared__ float Brow[PADW * W_];    // horizontal 5-max
    __shared__ float s_s[P_];            // cur scores
    __shared__ int   mk[P_];             // cur peak mask
    __shared__ int   pf[P_];             // exclusive prefix of mask; later rank for valid p
    __shared__ float cscore[P_];         // compacted valid scores (index order)
    __shared__ int   cpos[P_];           // compacted valid positions
    __shared__ int   inv[P_];            // slot -> position
    __shared__ int   scan[NTHR];
    __shared__ float w1f[16], b1f[8], w2f[64], b2f[8], w3f[8];
    __shared__ float redf[24];
    __shared__ int   redi[4];
    __shared__ float bcast[8];           // 0:b3  1:f_old.r 2:f_old.c  3:S_cur 4:Mr 5:Mc

    // ---------------- fold BN into linear weights ----------------
    if (t < 8) {
        float sc1 = g1[t] / sqrtf(v1[t] + 1e-5f);
        w1f[2*t+0] = W1[2*t+0] * sc1;
        w1f[2*t+1] = W1[2*t+1] * sc1;
        b1f[t]     = (b1[t] - m1[t]) * sc1 + be1[t];
        float sc2 = g2[t] / sqrtf(v2[t] + 1e-5f);
        b2f[t]     = (b2[t] - m2[t]) * sc2 + be2[t];
        w3f[t]     = W3[t];
    }
    if (t == 8) bcast[0] = b3[0];
    if (t < 64) {
        int o = t >> 3;
        float sc2 = g2[o] / sqrtf(v2[o] + 1e-5f);
        w2f[t] = W2[t] * sc2;
    }

    // ---------------- argmax of anno row (first max wins) ----------------
    const float* yrow = anno + (size_t)b * P_;
    float bv = -INFINITY; int bi = P_;
    for (int p = t; p < P_; p += NTHR) {
        float v = yrow[p];
        if (v > bv) { bv = v; bi = p; }
    }
    for (int m = 32; m > 0; m >>= 1) {
        float ov = __shfl_xor(bv, m);
        int   oi = __shfl_xor(bi, m);
        if (ov > bv || (ov == bv && oi < bi)) { bv = ov; bi = oi; }
    }
    if (lane == 0) { redf[wv] = bv; redi[wv] = bi; }
    __syncthreads();
    bv = redf[0]; bi = redi[0];
    #pragma unroll
    for (int w = 1; w < 4; w++) {
        float ov = redf[w]; int oi = redi[w];
        if (ov > bv || (ov == bv && oi < bi)) { bv = ov; bi = oi; }
    }
    const int gy = bi / W_, gx = bi - (bi / W_) * W_;
    __syncthreads();   // redf/redi free for reuse

    // ---------------- helpers ----------------
    auto load_and_rowmax = [&](const float* __restrict__ src) {
        for (int i = t; i < PADW * PADW; i += NTHR) {
            int py = i / PADW, px = i - (i / PADW) * PADW;
            int y = py - 2, x = px - 2;
            float v = -INFINITY;
            if (y >= 0 && y < H_ && x >= 0 && x < W_) v = src[y * W_ + x];
            A[i] = v;
        }
        __syncthreads();
        for (int i = t; i < PADW * W_; i += NTHR) {
            int py = i / W_, x = i - (i / W_) * W_;
            float m = -INFINITY;
            if (py >= 2 && py <= 24) {
                const float* r = &A[py * PADW + x];
                m = fmaxf(fmaxf(fmaxf(r[0], r[1]), fmaxf(r[2], r[3])), r[4]);
            }
            Brow[i] = m;
        }
        __syncthreads();
    };
    auto wsum = [&](float v) {
        #pragma unroll
        for (int m = 32; m > 0; m >>= 1) v += __shfl_xor(v, m);
        return v;
    };

    const float* sold = tscores + (size_t)b * P_;
    const float* scur = tscores + (size_t)B * P_ + (size_t)b * P_;

    // ---------------- OLD map: stats + nearest-peak-to-gc ----------------
    load_and_rowmax(sold);
    float So = 0.f, Mor = 0.f, Moc = 0.f;
    float nd2 = INFINITY, ns = -INFINITY; int np = 0;
    for (int p = t; p < P_; p += NTHR) {
        int y = p / W_, x = p - y * W_;
        float s  = A[(y + 2) * PADW + (x + 2)];
        const float* c = &Brow[y * W_ + x];
        float sm = fmaxf(fmaxf(fmaxf(c[0], c[W_]), fmaxf(c[2*W_], c[3*W_])), c[4*W_]);
        if (s == sm && s > TH_) {
            So += s; Mor += s * (float)y; Moc += s * (float)x;
            int dy = gy - y, dx = gx - x;
            float d2 = (float)(dy * dy + dx * dx);
            if (d2 < nd2 || (d2 == nd2 && (s > ns || (s == ns && p < np)))) {
                nd2 = d2; ns = s; np = p;
            }
        }
    }
    So = wsum(So); Mor = wsum(Mor); Moc = wsum(Moc);
    #pragma unroll
    for (int m = 32; m > 0; m >>= 1) {
        float od2 = __shfl_xor(nd2, m), os = __shfl_xor(ns, m);
        int   op  = __shfl_xor(np, m);
        if (od2 < nd2 || (od2 == nd2 && (os > ns || (os == ns && op < np)))) {
            nd2 = od2; ns = os; np = op;
        }
    }
    __syncthreads();
    if (lane == 0) {
        redf[wv] = So; redf[4 + wv] = Mor; redf[8 + wv] = Moc;
        redf[12 + wv] = nd2; redf[16 + wv] = ns; redi[wv] = np;
    }
    __syncthreads();
    if (t == 0) {
        float S = 0, Mr = 0, Mc = 0, d2 = INFINITY, ss = -INFINITY; int pp = 0;
        #pragma unroll
        for (int w = 0; w < 4; w++) {
            S += redf[w]; Mr += redf[4 + w]; Mc += redf[8 + w];
            float od2 = redf[12 + w], os = redf[16 + w]; int op = redi[w];
            if (od2 < d2 || (od2 == d2 && (os > ss || (os == ss && op < pp)))) {
                d2 = od2; ss = os; pp = op;
            }
        }
        int cy = pp / W_, cx = pp - (pp / W_) * W_;
        bcast[1] = S * (float)cy - Mr;   // f_old row  (S==0 -> exactly 0)
        bcast[2] = S * (float)cx - Mc;   // f_old col
    }
    __syncthreads();

    // ---------------- CUR map: mask + stats ----------------
    load_and_rowmax(scur);
    float Sc = 0.f, Mcr = 0.f, Mcc = 0.f;
    for (int p = t; p < P_; p += NTHR) {
        int y = p / W_, x = p - y * W_;
        float s  = A[(y + 2) * PADW + (x + 2)];
        const float* c = &Brow[y * W_ + x];
        float sm = fmaxf(fmaxf(fmaxf(c[0], c[W_]), fmaxf(c[2*W_], c[3*W_])), c[4*W_]);
        int m = (s == sm && s > TH_) ? 1 : 0;
        s_s[p] = s; mk[p] = m;
        if (m) { Sc += s; Mcr += s * (float)y; Mcc += s * (float)x; }
    }
    Sc = wsum(Sc); Mcr = wsum(Mcr); Mcc = wsum(Mcc);
    __syncthreads();
    if (lane == 0) { redf[wv] = Sc; redf[4 + wv] = Mcr; redf[8 + wv] = Mcc; }
    __syncthreads();
    if (t == 0) {
        bcast[3] = redf[0] + redf[1] + redf[2] + redf[3];
        bcast[4] = redf[4] + redf[5] + redf[6] + redf[7];
        bcast[5] = redf[8] + redf[9] + redf[10] + redf[11];
    }

    // ---------------- prefix scan over mask (chunked Hillis-Steele) ----------------
    int c0 = t * 3; if (c0 > P_) c0 = P_;
    int c1 = t * 3 + 3; if (c1 > P_) c1 = P_;
    int loc = 0;
    for (int p = c0; p < c1; p++) loc += mk[p];
    scan[t] = loc;
    __syncthreads();
    for (int off = 1; off < NTHR; off <<= 1) {
        int v = (t >= off) ? scan[t - off] : 0;
        __syncthreads();
        scan[t] += v;
        __syncthreads();
    }
    const int K = scan[NTHR - 1];
    int base = scan[t] - loc;
    for (int p = c0; p < c1; p++) {
        pf[p] = base;
        if (mk[p]) { cscore[base] = s_s[p]; cpos[base] = p; base++; }
    }
    __syncthreads();

    // ---------------- rank valid peaks: (score desc, pos asc) ----------------
    for (int i = t; i < K; i += NTHR) {
        float si = cscore[i]; int pi = cpos[i]; int r = 0;
        for (int j = 0; j < K; j++) {
            float sj = cscore[j]; int pj = cpos[j];
            r += (sj > si || (sj == si && pj < pi)) ? 1 : 0;
        }
        pf[pi] = r;   // overwrite: for valid p, pf[p] is now the sorted rank
    }
    __syncthreads();

    // ---------------- inverse permutation: slot -> position ----------------
    for (int p = t; p < P_; p += NTHR) {
        int slot = mk[p] ? pf[p] : (K + p - pf[p]);
        inv[slot] = p;
    }
    __syncthreads();

    // ---------------- per-slot outputs (coalesced) ----------------
    const float foldr = bcast[1], foldc = bcast[2];
    const float S = bcast[3], Mr = bcast[4], Mc = bcast[5];
    const float b3v = bcast[0];
    const size_t BP = (size_t)B * P_;
    float* out_pred = out;
    float* out_c    = out + BP;        // [B,P,2]
    float* out_s    = out + 3 * BP;
    float* out_v    = out + 4 * BP;
    const size_t rowbase = (size_t)b * P_;

    for (int j = t; j < P_; j += NTHR) {
        int p = inv[j];
        int m = mk[p];
        float s = s_s[p];
        int y = p / W_, x = p - (p / W_) * W_;
        float rowf = (float)y, colf = (float)x;
        float fcr = S * rowf - Mr;
        float fcc = S * colf - Mc;
        float dr = foldr - fcr, dc = foldc - fcc;
        float err = sqrtf(fmaxf(dr * dr + dc * dc, 1e-24f));

        float h1[8];
        #pragma unroll
        for (int o = 0; o < 8; o++)
            h1[o] = fmaxf(fmaf(err, w1f[2*o], fmaf(s, w1f[2*o+1], b1f[o])), 0.f);
        float pred = b3v;
        #pragma unroll
        for (int o = 0; o < 8; o++) {
            float z = b2f[o];
            #pragma unroll
            for (int i = 0; i < 8; i++) z = fmaf(h1[i], w2f[o*8+i], z);
            pred = fmaf(fmaxf(z, 0.f), w3f[o], pred);
        }

        out_pred[rowbase + j] = m ? pred : 0.f;
        ((float2*)out_c)[rowbase + j] = make_float2(rowf, colf);
        out_s[rowbase + j] = s;
        out_v[rowbase + j] = m ? 1.f : 0.f;
    }
}

extern "C" void kernel_launch(void* const* d_in, const int* in_sizes, int n_in,
                              void* d_out, int out_size, void* d_ws, size_t ws_size,
                              hipStream_t stream) {
    const int B = in_sizes[0] / (2 * P_);
    hipLaunchKernelGGL(peak_kernel, dim3(B), dim3(NTHR), 0, stream,
        (const float*)d_in[0], (const float*)d_in[1],
        (const float*)d_in[2], (const float*)d_in[3], (const float*)d_in[4],
        (const float*)d_in[5], (const float*)d_in[6], (const float*)d_in[7],
        (const float*)d_in[8], (const float*)d_in[9], (const float*)d_in[10],
        (const float*)d_in[11], (const float*)d_in[12], (const float*)d_in[13],
        (const float*)d_in[14], (const float*)d_in[15],
        (float*)d_out, B);
}

// Round 2
// 110.525 us; speedup vs baseline: 3.0417x; 3.0417x over previous
//
#include <hip/hip_runtime.h>
#include <math.h>

#define H_   23
#define W_   23
#define P_   529
#define TH_  0.05f
#define NC   9            // ceil(529/64) chunks per wave
#define CAP  96           // max compacted peaks (geometric max is 64 for strict peaks)
#define WPB  4            // waves (batch elements) per block
#define NTHR (WPB * 64)
#define WFLO (2 * P_ + 112)  // floats per wave LDS partition

// wave-synchronous fence: per-wave LDS ops are executed in order by HW;
// this only stops the compiler from reordering memory ops across phases.
#define WSYNC() do { asm volatile("" ::: "memory"); __builtin_amdgcn_wave_barrier(); } while (0)

__global__ __launch_bounds__(NTHR, 3) void peak_kernel(
    const float* __restrict__ tscores,  // [2,B,P]
    const float* __restrict__ anno,     // [1,B,P]
    const float* __restrict__ W1, const float* __restrict__ b1,
    const float* __restrict__ g1, const float* __restrict__ be1,
    const float* __restrict__ m1, const float* __restrict__ v1,
    const float* __restrict__ W2, const float* __restrict__ b2,
    const float* __restrict__ g2, const float* __restrict__ be2,
    const float* __restrict__ m2, const float* __restrict__ v2,
    const float* __restrict__ W3, const float* __restrict__ b3,
    float* __restrict__ out, int B)
{
    const int t  = threadIdx.x;
    const int l  = t & 63;
    const int wv = t >> 6;
    const int b  = blockIdx.x * WPB + wv;
    if (b >= B) return;   // safe: no block-wide barriers anywhere

    __shared__ float lds[WPB * WFLO];
    float* m  = lds + wv * WFLO;   // [529] raw map (old, then cur)
    float* r  = m + P_;            // [529] rowmax; later overlaid: cs/cp/rk
    float* wt = r + P_;            // [112] folded MLP weights
    float* cs = r;                 // [CAP] compacted scores
    int*   cp = (int*)(r + CAP);   // [CAP] compacted positions
    int*   rk = (int*)(r + 2*CAP); // [CAP] rank of compacted entry

    const unsigned long long ltm = (1ull << l) - 1ull;

    // ---------------- fold BN into linear weights (per wave, wave-private) ----
    {
        int o = l >> 3;
        float sc2o = g2[o] / sqrtf(v2[o] + 1e-5f);
        wt[24 + l] = W2[l] * sc2o;                       // w2f[64]
        if (l < 8) {
            float sc1 = g1[l] / sqrtf(v1[l] + 1e-5f);
            wt[2*l]     = W1[2*l] * sc1;                 // w1f[16]
            wt[2*l + 1] = W1[2*l + 1] * sc1;
            wt[16 + l]  = (b1[l] - m1[l]) * sc1 + be1[l];// b1f[8]
            float sc2 = g2[l] / sqrtf(v2[l] + 1e-5f);
            wt[88 + l]  = (b2[l] - m2[l]) * sc2 + be2[l];// b2f[8]
            wt[96 + l]  = W3[l];                         // w3f[8]
            if (l == 0) wt[104] = b3[0];
        }
    }

    // ---------------- issue global loads early ----------------
    const float* yrow = anno + (size_t)b * P_;
    const float* sold = tscores + (size_t)b * P_;
    const float* scur = tscores + (size_t)B * P_ + (size_t)b * P_;
    float ao[NC], so[NC], sc[NC];
    #pragma unroll
    for (int c = 0; c < NC; c++) { int p = 64*c + l; ao[c] = (p < P_) ? yrow[p] : -INFINITY; }
    #pragma unroll
    for (int c = 0; c < NC; c++) { int p = 64*c + l; so[c] = (p < P_) ? sold[p] : 0.f; }
    #pragma unroll
    for (int c = 0; c < NC; c++) { int p = 64*c + l; sc[c] = (p < P_) ? scur[p] : 0.f; }

    // ---------------- anno argmax (first max wins) ----------------
    float bv = -INFINITY; int bi = 0x7fffffff;
    #pragma unroll
    for (int c = 0; c < NC; c++) {
        int p = 64*c + l;
        if (p < P_ && ao[c] > bv) { bv = ao[c]; bi = p; }
    }
    #pragma unroll
    for (int d = 32; d > 0; d >>= 1) {
        float ov = __shfl_xor(bv, d); int oi = __shfl_xor(bi, d);
        if (ov > bv || (ov == bv && oi < bi)) { bv = ov; bi = oi; }
    }
    const int gy = bi / W_, gx = bi - (bi / W_) * W_;

    // ---------------- OLD map: peaks + stats + nearest-to-gc ----------------
    #pragma unroll
    for (int c = 0; c < NC; c++) { int p = 64*c + l; if (p < P_) m[p] = so[c]; }
    WSYNC();
    #pragma unroll
    for (int c = 0; c < NC; c++) {
        int p = 64*c + l;
        if (p < P_) {
            int y = p / W_, x = p - y * W_;
            const float* row = &m[y * W_];
            float mx = row[x];
            if (x >= 1)      mx = fmaxf(mx, row[x-1]);
            if (x >= 2)      mx = fmaxf(mx, row[x-2]);
            if (x <= W_-2)   mx = fmaxf(mx, row[x+1]);
            if (x <= W_-3)   mx = fmaxf(mx, row[x+2]);
            r[p] = mx;
        }
    }
    WSYNC();
    float So = 0.f, Mor = 0.f, Moc = 0.f;
    float nd2 = INFINITY, ns = -INFINITY; int np = 0;
    #pragma unroll
    for (int c = 0; c < NC; c++) {
        int p = 64*c + l;
        if (p < P_) {
            int y = p / W_, x = p - y * W_;
            float s = so[c];
            float sm = r[p];
            if (y >= 1)    sm = fmaxf(sm, r[p - W_]);
            if (y >= 2)    sm = fmaxf(sm, r[p - 2*W_]);
            if (y <= H_-2) sm = fmaxf(sm, r[p + W_]);
            if (y <= H_-3) sm = fmaxf(sm, r[p + 2*W_]);
            if (s == sm && s > TH_) {
                So += s; Mor += s * (float)y; Moc += s * (float)x;
                int dy = gy - y, dx = gx - x;
                float d2 = (float)(dy*dy + dx*dx);
                if (d2 < nd2 || (d2 == nd2 && (s > ns || (s == ns && p < np)))) {
                    nd2 = d2; ns = s; np = p;
                }
            }
        }
    }
    #pragma unroll
    for (int d = 32; d > 0; d >>= 1) {
        So += __shfl_xor(So, d); Mor += __shfl_xor(Mor, d); Moc += __shfl_xor(Moc, d);
        float od2 = __shfl_xor(nd2, d), os = __shfl_xor(ns, d); int op = __shfl_xor(np, d);
        if (od2 < nd2 || (od2 == nd2 && (os > ns || (os == ns && op < np)))) {
            nd2 = od2; ns = os; np = op;
        }
    }
    const int cy = np / W_, cx = np - (np / W_) * W_;
    const float foldr = So * (float)cy - Mor;   // f_old (exactly 0 when no peaks)
    const float foldc = So * (float)cx - Moc;

    // ---------------- CUR map: peaks + stats ----------------
    WSYNC();
    #pragma unroll
    for (int c = 0; c < NC; c++) { int p = 64*c + l; if (p < P_) m[p] = sc[c]; }
    WSYNC();
    #pragma unroll
    for (int c = 0; c < NC; c++) {
        int p = 64*c + l;
        if (p < P_) {
            int y = p / W_, x = p - y * W_;
            const float* row = &m[y * W_];
            float mx = row[x];
            if (x >= 1)      mx = fmaxf(mx, row[x-1]);
            if (x >= 2)      mx = fmaxf(mx, row[x-2]);
            if (x <= W_-2)   mx = fmaxf(mx, row[x+1]);
            if (x <= W_-3)   mx = fmaxf(mx, row[x+2]);
            r[p] = mx;
        }
    }
    WSYNC();
    float Sc = 0.f, Mcr = 0.f, Mcc = 0.f;
    int vb = 0;
    #pragma unroll
    for (int c = 0; c < NC; c++) {
        int p = 64*c + l;
        if (p < P_) {
            int y = p / W_, x = p - y * W_;
            float s = sc[c];
            float sm = r[p];
            if (y >= 1)    sm = fmaxf(sm, r[p - W_]);
            if (y >= 2)    sm = fmaxf(sm, r[p - 2*W_]);
            if (y <= H_-2) sm = fmaxf(sm, r[p + W_]);
            if (y <= H_-3) sm = fmaxf(sm, r[p + 2*W_]);
            if (s == sm && s > TH_) {
                vb |= 1 << c;
                Sc += s; Mcr += s * (float)y; Mcc += s * (float)x;
            }
        }
    }
    #pragma unroll
    for (int d = 32; d > 0; d >>= 1) {
        Sc += __shfl_xor(Sc, d); Mcr += __shfl_xor(Mcr, d); Mcc += __shfl_xor(Mcc, d);
    }
    WSYNC();   // r is dead; reuse as cs/cp/rk

    // ---------------- compaction via ballot ----------------
    int K = 0;
    int base[NC];
    unsigned long long bits[NC];
    #pragma unroll
    for (int c = 0; c < NC; c++) {
        bool v = (vb >> c) & 1;
        unsigned long long bt = __ballot(v);
        bits[c] = bt; base[c] = K;
        int my = K + __popcll(bt & ltm);
        if (v && my < CAP) { cs[my] = sc[c]; cp[my] = 64*c + l; }
        K += __popcll(bt);
    }
    WSYNC();

    // ---------------- rank compacted peaks (score desc, pos asc) ----------------
    const int Kc = K > CAP ? CAP : K;
    for (int i = l; i < Kc; i += 64) {
        float si = cs[i]; int pi = cp[i]; int rr = 0;
        for (int j = 0; j < Kc; j++) {
            float sj = cs[j]; int pj = cp[j];
            rr += (sj > si || (sj == si && pj < pi)) ? 1 : 0;
        }
        rk[i] = rr;
    }
    WSYNC();

    // ---------------- MLP: layer 1 (h1 for all chunks), then o-interchanged L2/L3 ----
    float w1r[16], b1r[8];
    #pragma unroll
    for (int i = 0; i < 16; i++) w1r[i] = wt[i];
    #pragma unroll
    for (int i = 0; i < 8; i++)  b1r[i] = wt[16 + i];

    float h1[NC][8];
    #pragma unroll
    for (int c = 0; c < NC; c++) {
        int p = 64*c + l;
        int y = p / W_, x = p - y * W_;
        float fcr = Sc * (float)y - Mcr;
        float fcc = Sc * (float)x - Mcc;
        float dr = foldr - fcr, dc = foldc - fcc;
        float err = sqrtf(fmaxf(dr*dr + dc*dc, 1e-24f));
        float s = sc[c];
        #pragma unroll
        for (int o = 0; o < 8; o++)
            h1[c][o] = fmaxf(fmaf(err, w1r[2*o], fmaf(s, w1r[2*o+1], b1r[o])), 0.f);
    }
    float pred[NC];
    {
        float b3v = wt[104];
        #pragma unroll
        for (int c = 0; c < NC; c++) pred[c] = b3v;
    }
    #pragma unroll
    for (int o = 0; o < 8; o++) {
        float w2r[8];
        #pragma unroll
        for (int i = 0; i < 8; i++) w2r[i] = wt[24 + o*8 + i];
        float b2o = wt[88 + o], w3o = wt[96 + o];
        #pragma unroll
        for (int c = 0; c < NC; c++) {
            float z = b2o;
            #pragma unroll
            for (int i = 0; i < 8; i++) z = fmaf(h1[c][i], w2r[i], z);
            pred[c] = fmaf(fmaxf(z, 0.f), w3o, pred[c]);
        }
    }

    // ---------------- scatter outputs ----------------
    const size_t BP = (size_t)B * P_;
    float* out_pred = out;
    float* out_c    = out + BP;       // [B,P,2]
    float* out_s    = out + 3 * BP;
    float* out_v    = out + 4 * BP;
    const size_t rowbase = (size_t)b * P_;

    #pragma unroll
    for (int c = 0; c < NC; c++) {
        int p = 64*c + l;
        if (p < P_) {
            bool v = (vb >> c) & 1;
            int nb = base[c] + __popcll(bits[c] & ltm);   // #valid strictly before p
            int slot;
            if (v) slot = (nb < CAP) ? rk[nb] : nb;
            else   slot = K + p - nb;
            int y = p / W_, x = p - y * W_;
            out_pred[rowbase + slot] = v ? pred[c] : 0.f;
            ((float2*)out_c)[rowbase + slot] = make_float2((float)y, (float)x);
            out_s[rowbase + slot] = sc[c];
            out_v[rowbase + slot] = v ? 1.f : 0.f;
        }
    }
}

extern "C" void kernel_launch(void* const* d_in, const int* in_sizes, int n_in,
                              void* d_out, int out_size, void* d_ws, size_t ws_size,
                              hipStream_t stream) {
    const int B = in_sizes[0] / (2 * P_);
    hipLaunchKernelGGL(peak_kernel, dim3((B + WPB - 1) / WPB), dim3(NTHR), 0, stream,
        (const float*)d_in[0], (const float*)d_in[1],
        (const float*)d_in[2], (const float*)d_in[3], (const float*)d_in[4],
        (const float*)d_in[5], (const float*)d_in[6], (const float*)d_in[7],
        (const float*)d_in[8], (const float*)d_in[9], (const float*)d_in[10],
        (const float*)d_in[11], (const float*)d_in[12], (const float*)d_in[13],
        (const float*)d_in[14], (const float*)d_in[15],
        (float*)d_out, B);
}

// Round 3
// 70.915 us; speedup vs baseline: 4.7406x; 1.5586x over previous
//
#include <hip/hip_runtime.h>
#include <math.h>

#define H_   23
#define W_   23
#define P_   529
#define TH_  0.05f
#define NC   9            // ceil(529/64) chunks per wave
#define CAP  96           // max compacted peaks (geometric max is 64 for strict peaks)
#define WPB  4            // waves (batch elements) per block
#define NTHR (WPB * 64)
#define WFLO (2 * P_ + 112)  // floats per wave LDS partition

// wave-synchronous fence: per-wave LDS ops execute in program order across the
// whole wave (SIMD lockstep); this only stops compiler reordering across phases.
#define WSYNC() do { asm volatile("" ::: "memory"); __builtin_amdgcn_wave_barrier(); } while (0)

__global__ __launch_bounds__(NTHR, 8) void peak_kernel(
    const float* __restrict__ tscores,  // [2,B,P]
    const float* __restrict__ anno,     // [1,B,P]
    const float* __restrict__ W1, const float* __restrict__ b1,
    const float* __restrict__ g1, const float* __restrict__ be1,
    const float* __restrict__ m1, const float* __restrict__ v1,
    const float* __restrict__ W2, const float* __restrict__ b2,
    const float* __restrict__ g2, const float* __restrict__ be2,
    const float* __restrict__ m2, const float* __restrict__ v2,
    const float* __restrict__ W3, const float* __restrict__ b3,
    float* __restrict__ out, int B)
{
    const int t  = threadIdx.x;
    const int l  = t & 63;
    const int wv = t >> 6;
    const int b  = blockIdx.x * WPB + wv;

    __shared__ float lds[WPB * WFLO];
    float* m  = lds + wv * WFLO;   // [529] raw map (old, then cur — kept for out_s)
    float* r  = m + P_;            // [529] rowmax; later cs/cp/rk; later inv
    float* wt = r + P_;            // [112] folded MLP weights; later predslot
    float* cs = r;                 // [CAP] compacted scores
    int*   cp = (int*)(r + CAP);   // [CAP] compacted positions
    int*   rk = (int*)(r + 2*CAP); // [CAP] rank of compacted entry
    int*   ri = (int*)r;           // [529] inv: slot -> position (overlay, last)
    float* ps = wt;                // [CAP] pred staged by slot (overlay on weights)

    const unsigned long long ltm = (1ull << l) - 1ull;

    // ---------------- fold BN into linear weights (wave-private) ----------------
    {
        int o = l >> 3;
        float sc2o = g2[o] / sqrtf(v2[o] + 1e-5f);
        wt[24 + l] = W2[l] * sc2o;                       // w2f[64]
        if (l < 8) {
            float sc1 = g1[l] / sqrtf(v1[l] + 1e-5f);
            wt[2*l]     = W1[2*l] * sc1;                 // w1f[16]
            wt[2*l + 1] = W1[2*l + 1] * sc1;
            wt[16 + l]  = (b1[l] - m1[l]) * sc1 + be1[l];// b1f[8]
            float sc2 = g2[l] / sqrtf(v2[l] + 1e-5f);
            wt[88 + l]  = (b2[l] - m2[l]) * sc2 + be2[l];// b2f[8]
            wt[96 + l]  = W3[l];                         // w3f[8]
            if (l == 0) wt[104] = b3[0];
        }
    }

    // ---------------- issue global loads early ----------------
    const float* yrow = anno + (size_t)b * P_;
    const float* sold = tscores + (size_t)b * P_;
    const float* scur = tscores + (size_t)B * P_ + (size_t)b * P_;
    float ao[NC], so[NC], sc[NC];
    #pragma unroll
    for (int c = 0; c < NC; c++) { int p = 64*c + l; ao[c] = (p < P_) ? yrow[p] : -INFINITY; }
    #pragma unroll
    for (int c = 0; c < NC; c++) { int p = 64*c + l; so[c] = (p < P_) ? sold[p] : 0.f; }
    #pragma unroll
    for (int c = 0; c < NC; c++) { int p = 64*c + l; sc[c] = (p < P_) ? scur[p] : 0.f; }

    // ---------------- anno argmax (first max wins) ----------------
    float bv = -INFINITY; int bi = 0x7fffffff;
    #pragma unroll
    for (int c = 0; c < NC; c++) {
        int p = 64*c + l;
        if (p < P_ && ao[c] > bv) { bv = ao[c]; bi = p; }
    }
    #pragma unroll
    for (int d = 32; d > 0; d >>= 1) {
        float ov = __shfl_xor(bv, d); int oi = __shfl_xor(bi, d);
        if (ov > bv || (ov == bv && oi < bi)) { bv = ov; bi = oi; }
    }
    const int gy = bi / W_, gx = bi - (bi / W_) * W_;

    // ---------------- OLD map: peaks + stats + nearest-to-gc ----------------
    #pragma unroll
    for (int c = 0; c < NC; c++) { int p = 64*c + l; if (p < P_) m[p] = so[c]; }
    WSYNC();
    #pragma unroll
    for (int c = 0; c < NC; c++) {
        int p = 64*c + l;
        if (p < P_) {
            int y = p / W_, x = p - y * W_;
            const float* row = &m[y * W_];
            float mx = row[x];
            if (x >= 1)      mx = fmaxf(mx, row[x-1]);
            if (x >= 2)      mx = fmaxf(mx, row[x-2]);
            if (x <= W_-2)   mx = fmaxf(mx, row[x+1]);
            if (x <= W_-3)   mx = fmaxf(mx, row[x+2]);
            r[p] = mx;
        }
    }
    WSYNC();
    float So = 0.f, Mor = 0.f, Moc = 0.f;
    float nd2 = INFINITY, ns = -INFINITY; int np = 0;
    #pragma unroll
    for (int c = 0; c < NC; c++) {
        int p = 64*c + l;
        if (p < P_) {
            int y = p / W_, x = p - y * W_;
            float s = so[c];
            float sm = r[p];
            if (y >= 1)    sm = fmaxf(sm, r[p - W_]);
            if (y >= 2)    sm = fmaxf(sm, r[p - 2*W_]);
            if (y <= H_-2) sm = fmaxf(sm, r[p + W_]);
            if (y <= H_-3) sm = fmaxf(sm, r[p + 2*W_]);
            if (s == sm && s > TH_) {
                So += s; Mor += s * (float)y; Moc += s * (float)x;
                int dy = gy - y, dx = gx - x;
                float d2 = (float)(dy*dy + dx*dx);
                if (d2 < nd2 || (d2 == nd2 && (s > ns || (s == ns && p < np)))) {
                    nd2 = d2; ns = s; np = p;
                }
            }
        }
    }
    #pragma unroll
    for (int d = 32; d > 0; d >>= 1) {
        So += __shfl_xor(So, d); Mor += __shfl_xor(Mor, d); Moc += __shfl_xor(Moc, d);
        float od2 = __shfl_xor(nd2, d), os = __shfl_xor(ns, d); int op = __shfl_xor(np, d);
        if (od2 < nd2 || (od2 == nd2 && (os > ns || (os == ns && op < np)))) {
            nd2 = od2; ns = os; np = op;
        }
    }
    const int cy = np / W_, cx = np - (np / W_) * W_;
    const float foldr = So * (float)cy - Mor;   // f_old (exactly 0 when no peaks)
    const float foldc = So * (float)cx - Moc;

    // ---------------- CUR map: peaks + stats (m keeps cur scores) ----------------
    WSYNC();
    #pragma unroll
    for (int c = 0; c < NC; c++) { int p = 64*c + l; if (p < P_) m[p] = sc[c]; }
    WSYNC();
    #pragma unroll
    for (int c = 0; c < NC; c++) {
        int p = 64*c + l;
        if (p < P_) {
            int y = p / W_, x = p - y * W_;
            const float* row = &m[y * W_];
            float mx = row[x];
            if (x >= 1)      mx = fmaxf(mx, row[x-1]);
            if (x >= 2)      mx = fmaxf(mx, row[x-2]);
            if (x <= W_-2)   mx = fmaxf(mx, row[x+1]);
            if (x <= W_-3)   mx = fmaxf(mx, row[x+2]);
            r[p] = mx;
        }
    }
    WSYNC();
    float Sc = 0.f, Mcr = 0.f, Mcc = 0.f;
    int vb = 0;
    #pragma unroll
    for (int c = 0; c < NC; c++) {
        int p = 64*c + l;
        if (p < P_) {
            int y = p / W_, x = p - y * W_;
            float s = sc[c];
            float sm = r[p];
            if (y >= 1)    sm = fmaxf(sm, r[p - W_]);
            if (y >= 2)    sm = fmaxf(sm, r[p - 2*W_]);
            if (y <= H_-2) sm = fmaxf(sm, r[p + W_]);
            if (y <= H_-3) sm = fmaxf(sm, r[p + 2*W_]);
            if (s == sm && s > TH_) {
                vb |= 1 << c;
                Sc += s; Mcr += s * (float)y; Mcc += s * (float)x;
            }
        }
    }
    #pragma unroll
    for (int d = 32; d > 0; d >>= 1) {
        Sc += __shfl_xor(Sc, d); Mcr += __shfl_xor(Mcr, d); Mcc += __shfl_xor(Mcc, d);
    }
    WSYNC();   // rowmax r is dead; reuse as cs/cp/rk

    // ---------------- compaction via ballot ----------------
    int K = 0;
    int nb[NC];                       // #valid strictly before p, per chunk
    #pragma unroll
    for (int c = 0; c < NC; c++) {
        bool v = (vb >> c) & 1;
        unsigned long long bt = __ballot(v);
        int my = K + __popcll(bt & ltm);
        nb[c] = my;
        if (v && my < CAP) { cs[my] = sc[c]; cp[my] = 64*c + l; }
        K += __popcll(bt);
    }
    WSYNC();

    // ---------------- rank compacted peaks (score desc, pos asc) ----------------
    const int Kc = K > CAP ? CAP : K;
    for (int i = l; i < Kc; i += 64) {
        float si = cs[i]; int pi = cp[i]; int rr = 0;
        for (int j = 0; j < Kc; j++) {
            float sj = cs[j]; int pj = cp[j];
            rr += (sj > si || (sj == si && pj < pi)) ? 1 : 0;
        }
        rk[i] = rr;
    }
    WSYNC();

    // ---------------- MLP over compacted peaks only (<=2 passes) ----------------
    auto mlp = [&](int i, float& pv, int& rko) {
        int p = cp[i];
        float s = cs[i];
        rko = rk[i];
        int y = p / W_, x = p - (p / W_) * W_;
        float fcr = Sc * (float)y - Mcr;
        float fcc = Sc * (float)x - Mcc;
        float dr = foldr - fcr, dc = foldc - fcc;
        float err = sqrtf(fmaxf(dr*dr + dc*dc, 1e-24f));
        float h1[8];
        #pragma unroll
        for (int o = 0; o < 8; o++)
            h1[o] = fmaxf(fmaf(err, wt[2*o], fmaf(s, wt[2*o+1], wt[16+o])), 0.f);
        float pred = wt[104];
        #pragma unroll
        for (int o = 0; o < 8; o++) {
            float z = wt[88 + o];
            #pragma unroll
            for (int i2 = 0; i2 < 8; i2++) z = fmaf(h1[i2], wt[24 + o*8 + i2], z);
            pred = fmaf(fmaxf(z, 0.f), wt[96 + o], pred);
        }
        pv = pred;
    };
    float pv0 = 0.f, pv1 = 0.f; int rk0 = -1, rk1 = -1;
    if (l < Kc)      mlp(l, pv0, rk0);
    if (64 + l < Kc) mlp(64 + l, pv1, rk1);
    WSYNC();                      // all weight reads done before overlaying ps on wt
    if (rk0 >= 0 && rk0 < CAP) ps[rk0] = pv0;
    if (rk1 >= 0 && rk1 < CAP) ps[rk1] = pv1;

    // ---------------- slot per position (reads rk), then inv scatter ----------------
    int slot[NC];
    #pragma unroll
    for (int c = 0; c < NC; c++) {
        int p = 64*c + l;
        if (p < P_) {
            bool v = (vb >> c) & 1;
            int n = nb[c];
            slot[c] = v ? ((n < CAP) ? rk[n] : n) : (K + p - n);
        }
    }
    WSYNC();                      // rk reads done before ri overlays r
    #pragma unroll
    for (int c = 0; c < NC; c++) {
        int p = 64*c + l;
        if (p < P_) ri[slot[c]] = p;
    }
    WSYNC();

    // ---------------- linear, coalesced output ----------------
    const size_t BP = (size_t)B * P_;
    float* out_pred = out;
    float* out_c    = out + BP;        // [B,P,2]
    float* out_s    = out + 3 * BP;
    float* out_v    = out + 4 * BP;
    const size_t rowbase = (size_t)b * P_;

    #pragma unroll
    for (int c = 0; c < NC; c++) {
        int j = 64*c + l;
        if (j < P_) {
            int p = ri[j];
            int y = p / W_, x = p - (p / W_) * W_;
            bool val = j < K;
            float pv = (val && j < CAP) ? ps[j] : 0.f;
            float s  = m[p];
            out_pred[rowbase + j] = pv;
            ((float2*)out_c)[rowbase + j] = make_float2((float)y, (float)x);
            out_s[rowbase + j] = s;
            out_v[rowbase + j] = val ? 1.f : 0.f;
        }
    }
}

extern "C" void kernel_launch(void* const* d_in, const int* in_sizes, int n_in,
                              void* d_out, int out_size, void* d_ws, size_t ws_size,
                              hipStream_t stream) {
    const int B = in_sizes[0] / (2 * P_);
    hipLaunchKernelGGL(peak_kernel, dim3((B + WPB - 1) / WPB), dim3(NTHR), 0, stream,
        (const float*)d_in[0], (const float*)d_in[1],
        (const float*)d_in[2], (const float*)d_in[3], (const float*)d_in[4],
        (const float*)d_in[5], (const float*)d_in[6], (const float*)d_in[7],
        (const float*)d_in[8], (const float*)d_in[9], (const float*)d_in[10],
        (const float*)d_in[11], (const float*)d_in[12], (const float*)d_in[13],
        (const float*)d_in[14], (const float*)d_in[15],
        (float*)d_out, B);
}